// Round 6
// baseline (1109.982 us; speedup 1.0000x reference)
//
#include <hip/hip_runtime.h>
#include <math.h>

typedef __attribute__((ext_vector_type(8))) short short8;
typedef __attribute__((ext_vector_type(4))) float f32x4;
typedef unsigned short ushort_t;

#define B_    1024
#define EPSV  1e-5

__device__ __forceinline__ float sgn(float v){ return (v>0.f)?1.f:((v<0.f)?-1.f:0.f); }
__device__ __forceinline__ ushort_t sgnbits(float v){ return (v>0.f)?(ushort_t)0x3F80:((v<0.f)?(ushort_t)0xBF80:(ushort_t)0); }

// ============ conv1 (binarized in & w) + maxpool2 -> [B][196][64] f32 (ch 48..63 = 0) ============
__global__ __launch_bounds__(256) void k_conv1_pool(const float* __restrict__ x,
                                                    const float* __restrict__ w1,
                                                    float* __restrict__ p1){
  int idx = blockIdx.x*256 + threadIdx.x;
  if (idx >= B_*196*64) return;
  int c = idx & 63;
  int p = (idx >> 6) % 196;
  int b = (idx >> 6) / 196;
  if (c >= 48){ p1[idx] = 0.f; return; }
  int y = p/14, xq = p - y*14;
  const float* xb = x + (size_t)b*784;
  float w[9];
#pragma unroll
  for (int k=0;k<9;k++) w[k] = sgn(w1[c*9+k]);
  float sx[4][4];
#pragma unroll
  for (int dy=0; dy<4; dy++){
    int iy = 2*y-1+dy;
#pragma unroll
    for (int dx=0; dx<4; dx++){
      int ix = 2*xq-1+dx;
      sx[dy][dx] = (iy>=0 && iy<28 && ix>=0 && ix<28) ? sgn(xb[iy*28+ix]) : 0.f;
    }
  }
  float best = -1e30f;
#pragma unroll
  for (int py=0;py<2;py++)
#pragma unroll
    for (int px=0;px<2;px++){
      float acc = 0.f;
#pragma unroll
      for (int ky=0;ky<3;ky++)
#pragma unroll
        for (int kx=0;kx<3;kx++)
          acc += sx[py+ky][px+kx]*w[ky*3+kx];
      best = fmaxf(best, acc);
    }
  p1[idx] = best;   // bias b1 cancels in BN
}

// ============ layer-1 stats: channel-last [rows][64] ============
__global__ __launch_bounds__(256) void k_stats_cl64(const float* __restrict__ src,
                                                    double* __restrict__ sum,
                                                    double* __restrict__ sumsq,
                                                    long rows){
  int c = threadIdx.x & 63, sl = threadIdx.x >> 6;
  double a=0.0, q=0.0;
  long stride = (long)gridDim.y*4;
  for (long r = (long)blockIdx.y*4 + sl; r < rows; r += stride){
    double v = (double)src[r*64 + c];
    a += v; q += v*v;
  }
  __shared__ double sA[256], sQd[256];
  sA[threadIdx.x]=a; sQd[threadIdx.x]=q;
  __syncthreads();
  if (threadIdx.x < 64){
    a = sA[threadIdx.x] + sA[threadIdx.x+64] + sA[threadIdx.x+128] + sA[threadIdx.x+192];
    q = sQd[threadIdx.x] + sQd[threadIdx.x+64] + sQd[threadIdx.x+128] + sQd[threadIdx.x+192];
    atomicAdd(&sum[c], a); atomicAdd(&sumsq[c], q);
  }
}

// ============ reduce f32 partial arrays [nPart][C] -> f64 sum/sumsq ============
__global__ __launch_bounds__(256) void k_reduce_stats(const float* __restrict__ pS,
                                                      const float* __restrict__ pQ,
                                                      double* __restrict__ sum,
                                                      double* __restrict__ sumsq,
                                                      int C, int nPart){
  int c = blockIdx.x*256 + threadIdx.x;
  if (c >= C) return;
  int per = (nPart + gridDim.y - 1)/gridDim.y;
  int p0 = blockIdx.y*per, p1 = p0+per; if (p1 > nPart) p1 = nPart;
  double a=0.0, q=0.0;
  for (int p = p0; p < p1; ++p){
    a += (double)pS[(size_t)p*C + c];
    q += (double)pQ[(size_t)p*C + c];
  }
  atomicAdd(&sum[c], a); atomicAdd(&sumsq[c], q);
}

// ============ bn scale/shift ============
__global__ void k_bnparams(const double* __restrict__ sum, const double* __restrict__ sumsq,
                           const float* __restrict__ g, const float* __restrict__ be,
                           float* __restrict__ scale, float* __restrict__ shift,
                           int C, int validC, double invN){
  int c = blockIdx.x*blockDim.x + threadIdx.x;
  if (c >= C) return;
  if (c >= validC){ scale[c]=0.f; shift[c]=0.f; return; }
  double m   = sum[c]*invN;
  double var = sumsq[c]*invN - m*m;
  double s   = (double)g[c] / sqrt(var + EPSV);
  scale[c] = (float)s;
  shift[c] = (float)((double)be[c] - m*s);
}

// ============ bn + sign -> bf16 bits ============
__global__ __launch_bounds__(256) void k_norm_sign(const float* __restrict__ src,
                                                   ushort_t* __restrict__ dst,
                                                   const float* __restrict__ scale,
                                                   const float* __restrict__ shift,
                                                   int C, int S, int total){
  int i = blockIdx.x*256 + threadIdx.x;
  if (i >= total) return;
  int c = (i / S) % C;
  float v = fmaf(src[i], scale[c], shift[c]);
  dst[i] = sgnbits(v);
}

// ============ bn + htanh in place (fp32) ============
__global__ __launch_bounds__(256) void k_norm_htanh(float* __restrict__ buf,
                                                    const float* __restrict__ scale,
                                                    const float* __restrict__ shift,
                                                    int C, int total){
  int i = blockIdx.x*256 + threadIdx.x;
  if (i >= total) return;
  int c = i % C;
  float v = fmaf(buf[i], scale[c], shift[c]);
  buf[i] = fminf(fmaxf(v,-1.f),1.f);
}

// ============ weight prep ============
__global__ __launch_bounds__(256) void k_prep_w2(const float* __restrict__ w2, ushort_t* __restrict__ out){
  int idx = blockIdx.x*256 + threadIdx.x;
  if (idx >= 128*576) return;
  int oc = idx / 576, r = idx - oc*576;
  int kk = r >> 6, ic = r & 63;
  out[idx] = (ic < 48) ? sgnbits(w2[oc*432 + ic*9 + kk]) : (ushort_t)0;
}
__global__ __launch_bounds__(256) void k_prep_w3(const float* __restrict__ w3, ushort_t* __restrict__ out){
  int idx = blockIdx.x*256 + threadIdx.x;
  if (idx >= 256*1152) return;
  int oc = idx / 1152, r = idx - oc*1152;
  int kk = r >> 7, ic = r & 127;
  out[idx] = sgnbits(w3[oc*1152 + ic*9 + kk]);
}
__global__ __launch_bounds__(256) void k_prep_wf1(const float* __restrict__ wf1, ushort_t* __restrict__ out){
  int idx = blockIdx.x*256 + threadIdx.x;
  if (idx >= 2048*12544/4) return;
  const float4 v = *reinterpret_cast<const float4*>(&wf1[(size_t)idx*4]);
  ushort4 o;
  o.x = sgnbits(v.x); o.y = sgnbits(v.y); o.z = sgnbits(v.z); o.w = sgnbits(v.w);
  *reinterpret_cast<ushort4*>(&out[(size_t)idx*4]) = o;
}

// ============ conv2 MFMA (barrier-free K-loop, weights from L2): ============
// a1 [B][196][64]bf16 x w2b[128][9*64] -> c2 [B][196][128]f32 + fused stats
__global__ __launch_bounds__(256,2) void k_conv2_mfma(const ushort_t* __restrict__ a1,
                                                      const ushort_t* __restrict__ w2b,
                                                      float* __restrict__ c2,
                                                      float* __restrict__ pS,
                                                      float* __restrict__ pQ){
  __shared__ ushort_t sIn[256*64];     // 32 KB
  __shared__ float sRS[64], sRQ[64];
  int ocb = blockIdx.x*64;             // gridDim.x = 2
  int b   = blockIdx.y;
  int tid = threadIdx.x;
  {
    const uint4* src4 = reinterpret_cast<const uint4*>(a1 + (size_t)b*196*64);
    for (int i = tid; i < 2048; i += 256){
      int px = i >> 3, ch = i & 7;
      int py = px >> 4, pxx = px & 15;
      uint4 v = make_uint4(0u,0u,0u,0u);
      if (py>=1 && py<=14 && pxx>=1 && pxx<=14)
        v = src4[((py-1)*14 + (pxx-1))*8 + ch];
      *reinterpret_cast<uint4*>(&sIn[px*64 + ((ch ^ (px & 7))<<3)]) = v;
    }
  }
  if (tid < 64){ sRS[tid]=0.f; sRQ[tid]=0.f; }
  __syncthreads();
  int lane = tid & 63, wave = tid >> 6;
  int rA = lane & 15, kch = lane >> 4;
  const uint4* gW = reinterpret_cast<const uint4*>(w2b);  // row = 72 uint4
  size_t wrow[4];
#pragma unroll
  for (int n=0;n<4;n++) wrow[n] = (size_t)(ocb + n*16 + rA)*72 + kch;
  f32x4 acc[4][4];
#pragma unroll
  for (int t=0;t<4;t++)
#pragma unroll
    for (int n=0;n<4;n++) acc[t][n] = (f32x4){0.f,0.f,0.f,0.f};

  uint4 bA[4], bB[4];
#pragma unroll
  for (int n=0;n<4;n++){ bA[n] = gW[wrow[n]]; bB[n] = gW[wrow[n] + 4]; }

#define C2_MSTEP(S, BSLOT, PRE) { \
    short8 bF[4]; \
    _Pragma("unroll") for (int n=0;n<4;n++) bF[n] = *reinterpret_cast<short8*>(&BSLOT[n]); \
    if ((S)+2 < 18){ _Pragma("unroll") for (int n=0;n<4;n++) BSLOT[n] = gW[wrow[n] + ((S)+2)*4]; } \
    int kk9 = (S) >> 1; int ky = kk9/3, kx = kk9 - ky*3; \
    int chbase = (((S) & 1) << 2) + kch; \
    _Pragma("unroll") for (int t=0;t<4;t++){ \
      int m = t*4 + wave; \
      if (m < 13){ \
        int r = m*16 + rA; int rc = r < 196 ? r : 195; \
        int y = rc/14, xx = rc - y*14; \
        int px = (y+ky)*16 + (xx+kx); \
        short8 aF = *reinterpret_cast<const short8*>(&sIn[px*64 + ((chbase ^ (px&7))<<3)]); \
        _Pragma("unroll") for (int n=0;n<4;n++) \
          acc[t][n] = __builtin_amdgcn_mfma_f32_16x16x32_bf16(aF, bF[n], acc[t][n], 0,0,0); \
      } \
    } }

  for (int sp = 0; sp < 9; ++sp){
    int s0 = sp*2;
    C2_MSTEP(s0,   bA, )
    C2_MSTEP(s0+1, bB, )
  }
#undef C2_MSTEP

  // epilogue: write c2 + per-column stats (exact in f32: even ints, bounded)
  int colL = lane & 15, rg = lane >> 4;
#pragma unroll
  for (int n=0;n<4;n++){
    float csum = 0.f, csq = 0.f;
#pragma unroll
    for (int t=0;t<4;t++){
      int m = t*4 + wave;
      if (m < 13){
#pragma unroll
        for (int j=0;j<4;j++){
          int r = m*16 + rg*4 + j;
          if (r < 196){
            float v = acc[t][n][j];
            c2[((size_t)b*196 + r)*128 + ocb + n*16 + colL] = v;
            csum += v; csq += v*v;
          }
        }
      }
    }
    csum += __shfl_down(csum,32); csum += __shfl_down(csum,16);
    csq  += __shfl_down(csq, 32); csq  += __shfl_down(csq, 16);
    if (rg == 0){
      atomicAdd(&sRS[n*16+colL], csum);
      atomicAdd(&sRQ[n*16+colL], csq);
    }
  }
  __syncthreads();
  if (tid < 64){
    pS[(size_t)b*128 + ocb + tid] = sRS[tid];
    pQ[(size_t)b*128 + ocb + tid] = sRQ[tid];
  }
}

// ============ conv3 MFMA + maxpool (barrier-free K-loop, weights from L2): ============
// a2 [B][196][128]bf16 x w3b[256][9*128] -> p3 [B][256][49]f32 + fused stats
__global__ __launch_bounds__(256,2) void k_conv3_mfma_pool(const ushort_t* __restrict__ a2,
                                                           const ushort_t* __restrict__ w3b,
                                                           float* __restrict__ p3,
                                                           float* __restrict__ pS,
                                                           float* __restrict__ pQ){
  __shared__ ushort_t sIn[256*128];    // 64 KB (pool buffer aliases)
  int ocb = blockIdx.x*64;             // gridDim.x = 4
  int b   = blockIdx.y;
  int tid = threadIdx.x;
  {
    const uint4* src4 = reinterpret_cast<const uint4*>(a2 + (size_t)b*196*128);
    for (int i = tid; i < 4096; i += 256){
      int px = i >> 4, ch = i & 15;
      int py = px >> 4, pxx = px & 15;
      uint4 v = make_uint4(0u,0u,0u,0u);
      if (py>=1 && py<=14 && pxx>=1 && pxx<=14)
        v = src4[((py-1)*14 + (pxx-1))*16 + ch];
      *reinterpret_cast<uint4*>(&sIn[px*128 + ((ch ^ (px & 15))<<3)]) = v;
    }
  }
  __syncthreads();
  int lane = tid & 63, wave = tid >> 6;
  int rA = lane & 15, kch = lane >> 4;
  const uint4* gW = reinterpret_cast<const uint4*>(w3b);  // row = 144 uint4
  size_t wrow[4];
#pragma unroll
  for (int n=0;n<4;n++) wrow[n] = (size_t)(ocb + n*16 + rA)*144 + kch;
  f32x4 acc[4][4];
#pragma unroll
  for (int t=0;t<4;t++)
#pragma unroll
    for (int n=0;n<4;n++) acc[t][n] = (f32x4){0.f,0.f,0.f,0.f};

  uint4 bA[4], bB[4];
#pragma unroll
  for (int n=0;n<4;n++){ bA[n] = gW[wrow[n]]; bB[n] = gW[wrow[n] + 4]; }

#define C3_MSTEP(S, BSLOT) { \
    short8 bF[4]; \
    _Pragma("unroll") for (int n=0;n<4;n++) bF[n] = *reinterpret_cast<short8*>(&BSLOT[n]); \
    if ((S)+2 < 36){ _Pragma("unroll") for (int n=0;n<4;n++) BSLOT[n] = gW[wrow[n] + ((S)+2)*4]; } \
    int kk9 = (S) >> 2; int ky = kk9/3, kx = kk9 - ky*3; \
    int chbase = (((S) & 3) << 2) + kch; \
    _Pragma("unroll") for (int t=0;t<4;t++){ \
      int m = t*4 + wave; \
      if (m < 13){ \
        int r = m*16 + rA; int rc = r < 196 ? r : 195; \
        int y = rc/14, xx = rc - y*14; \
        int px = (y+ky)*16 + (xx+kx); \
        short8 aF = *reinterpret_cast<const short8*>(&sIn[px*128 + ((chbase ^ (px&15))<<3)]); \
        _Pragma("unroll") for (int n=0;n<4;n++) \
          acc[t][n] = __builtin_amdgcn_mfma_f32_16x16x32_bf16(aF, bF[n], acc[t][n], 0,0,0); \
      } \
    } }

  for (int sp = 0; sp < 18; ++sp){
    int s0 = sp*2;
    C3_MSTEP(s0,   bA)
    C3_MSTEP(s0+1, bB)
  }
#undef C3_MSTEP

  // pool: sPool aliases sIn: [64][213] f32 = 54.5 KB
  __syncthreads();                 // all waves done reading sIn
  float* sPool = reinterpret_cast<float*>(sIn);
  int colL = lane & 15, rg = lane >> 4;
#pragma unroll
  for (int t=0;t<4;t++){
    int m = t*4 + wave;
    if (m < 13){
#pragma unroll
      for (int n=0;n<4;n++)
#pragma unroll
        for (int j=0;j<4;j++){
          int r = m*16 + rg*4 + j;
          if (r < 196) sPool[(n*16+colL)*213 + r] = acc[t][n][j];
        }
    }
  }
  __syncthreads();
  // pool-read + stats: 4 threads per oc, shuffle-reduce (no LDS atomics)
  {
    int oc = tid >> 2, part = tid & 3;
    float ls = 0.f, lq = 0.f;
    const float* rowp = &sPool[oc*213];
    float* outp = &p3[((size_t)b*256 + ocb + oc)*49];
    for (int ci = 0; ci < 13; ++ci){
      int cell = part*13 + ci;
      if (cell < 49){
        int cy = cell/7, cx = cell - cy*7;
        const float* rp = rowp + cy*28 + cx*2;
        float v = fmaxf(fmaxf(rp[0],rp[1]), fmaxf(rp[14],rp[15]));
        outp[cell] = v;            // bias b3 cancels in BN
        ls += v; lq += v*v;
      }
    }
    ls += __shfl_down(ls,1); ls += __shfl_down(ls,2);
    lq += __shfl_down(lq,1); lq += __shfl_down(lq,2);
    if (part == 0){
      pS[(size_t)b*256 + ocb + oc] = ls;
      pQ[(size_t)b*256 + ocb + oc] = lq;
    }
  }
}

// ============ fc1 MFMA: a3 [1024][12544] x wf1b [2048][12544]^T -> f1 [1024][2048] + col stats ============
#define SWZF(o,c) ( ((o)<<7) + ((((c) ^ ((o)&7)) & 7) << 4) )
__global__ __launch_bounds__(256,2) void k_fc1_mfma(const ushort_t* __restrict__ A,
                                                    const ushort_t* __restrict__ Bw,
                                                    float* __restrict__ f1,
                                                    float* __restrict__ pS,
                                                    float* __restrict__ pQ){
  __shared__ char As[2][8192];    // [64 rows][128B], SWZF
  __shared__ char Bs[2][16384];   // [128 rows][128B], SWZF
  __shared__ float sCS[128], sCQ[128];
  int id = blockIdx.x;
  int bm = (id & 15) << 6, bn = (id >> 4) << 7;
  int tid = threadIdx.x;
  int cS = tid & 7;
  int rS = tid >> 3;              // 0..31
  const uint4* gA = reinterpret_cast<const uint4*>(A);   // row = 1568 uint4
  const uint4* gB = reinterpret_cast<const uint4*>(Bw);
  {
    *reinterpret_cast<uint4*>(&As[0][SWZF(rS,   cS)]) = gA[(size_t)(bm+rS   )*1568 + cS];
    *reinterpret_cast<uint4*>(&As[0][SWZF(rS+32,cS)]) = gA[(size_t)(bm+rS+32)*1568 + cS];
#pragma unroll
    for (int j=0;j<4;j++)
      *reinterpret_cast<uint4*>(&Bs[0][SWZF(rS+j*32,cS)]) = gB[(size_t)(bn+rS+j*32)*1568 + cS];
  }
  if (tid < 128){ sCS[tid]=0.f; sCQ[tid]=0.f; }
  __syncthreads();
  int lane = tid & 63, wave = tid >> 6;
  int rA = lane & 15, kch = lane >> 4;
  int wm = wave & 1, wn = wave >> 1;
  f32x4 acc[2][4];
#pragma unroll
  for (int i=0;i<2;i++)
#pragma unroll
    for (int n=0;n<4;n++) acc[i][n] = (f32x4){0.f,0.f,0.f,0.f};

  for (int s = 0; s < 196; ++s){
    int cur = s & 1;
    uint4 pa0, pa1, pb[4];
    if (s < 195){
      size_t k0 = (size_t)(s+1)*8 + cS;
      pa0 = gA[(size_t)(bm+rS   )*1568 + k0];
      pa1 = gA[(size_t)(bm+rS+32)*1568 + k0];
#pragma unroll
      for (int j=0;j<4;j++)
        pb[j] = gB[(size_t)(bn+rS+j*32)*1568 + k0];
    }
#pragma unroll
    for (int u = 0; u < 2; ++u){
      short8 aF[2], bF[4];
#pragma unroll
      for (int i=0;i<2;i++){
        int ro = wm*32 + i*16 + rA;
        aF[i] = *reinterpret_cast<const short8*>(&As[cur][SWZF(ro, u*4+kch)]);
      }
#pragma unroll
      for (int n=0;n<4;n++){
        int co = wn*64 + n*16 + rA;
        bF[n] = *reinterpret_cast<const short8*>(&Bs[cur][SWZF(co, u*4+kch)]);
      }
#pragma unroll
      for (int i=0;i<2;i++)
#pragma unroll
        for (int n=0;n<4;n++)
          acc[i][n] = __builtin_amdgcn_mfma_f32_16x16x32_bf16(aF[i], bF[n], acc[i][n], 0,0,0);
    }
    if (s < 195){
      *reinterpret_cast<uint4*>(&As[cur^1][SWZF(rS,   cS)]) = pa0;
      *reinterpret_cast<uint4*>(&As[cur^1][SWZF(rS+32,cS)]) = pa1;
#pragma unroll
      for (int j=0;j<4;j++)
        *reinterpret_cast<uint4*>(&Bs[cur^1][SWZF(rS+j*32,cS)]) = pb[j];
    }
    __syncthreads();
  }
  int colL = lane & 15, rg = lane >> 4;
#pragma unroll
  for (int n=0;n<4;n++){
    float ls = 0.f, lq = 0.f;
#pragma unroll
    for (int i=0;i<2;i++)
#pragma unroll
      for (int j=0;j<4;j++){
        int r = bm + wm*32 + i*16 + rg*4 + j;
        float v = acc[i][n][j];
        f1[(size_t)r*2048 + bn + wn*64 + n*16 + colL] = v;
        ls += v; lq += v*v;
      }
    ls += __shfl_down(ls,32); ls += __shfl_down(ls,16);
    lq += __shfl_down(lq,32); lq += __shfl_down(lq,16);
    if (rg == 0){
      atomicAdd(&sCS[wn*64 + n*16 + colL], ls);
      atomicAdd(&sCQ[wn*64 + n*16 + colL], lq);
    }
  }
  __syncthreads();
  if (tid < 128){
    pS[(size_t)(id&15)*2048 + bn + tid] = sCS[tid];
    pQ[(size_t)(id&15)*2048 + bn + tid] = sCQ[tid];
  }
}

// ============ fc2 + log_softmax ============
__global__ __launch_bounds__(256) void k_fc2_lsm(const float* __restrict__ h,
                                                 const float* __restrict__ W,
                                                 const float* __restrict__ bias,
                                                 float* __restrict__ out){
  int b = blockIdx.x;
  const float* hb = h + (size_t)b*2048;
  float acc[10];
#pragma unroll
  for (int o=0;o<10;o++) acc[o]=0.f;
  for (int k=threadIdx.x; k<2048; k+=256){
    float v = hb[k];
#pragma unroll
    for (int o=0;o<10;o++) acc[o] += v*W[o*2048+k];
  }
  __shared__ float red[4][10];
  int wv = threadIdx.x>>6, lanev = threadIdx.x&63;
#pragma unroll
  for (int o=0;o<10;o++){
    float r = acc[o];
    for (int off=32; off>0; off>>=1) r += __shfl_down(r, off);
    if (lanev==0) red[wv][o]=r;
  }
  __syncthreads();
  if (threadIdx.x==0){
    float lg[10], mx=-1e30f;
#pragma unroll
    for (int o=0;o<10;o++){ lg[o]=red[0][o]+red[1][o]+red[2][o]+red[3][o]+bias[o]; mx=fmaxf(mx,lg[o]); }
    float se=0.f;
#pragma unroll
    for (int o=0;o<10;o++) se += expf(lg[o]-mx);
    float lse = mx + logf(se);
#pragma unroll
    for (int o=0;o<10;o++) out[(size_t)b*10+o] = lg[o]-lse;
  }
}

// ================= launch =================
extern "C" void kernel_launch(void* const* d_in, const int* in_sizes, int n_in,
                              void* d_out, int out_size, void* d_ws, size_t ws_size,
                              hipStream_t stream){
  (void)in_sizes; (void)n_in; (void)out_size; (void)ws_size;
  const float* x   = (const float*)d_in[0];
  const float* w1  = (const float*)d_in[1];
  const float* g1  = (const float*)d_in[3];
  const float* be1 = (const float*)d_in[4];
  const float* w2  = (const float*)d_in[5];
  const float* g2  = (const float*)d_in[7];
  const float* be2 = (const float*)d_in[8];
  const float* w3  = (const float*)d_in[9];
  const float* g3  = (const float*)d_in[11];
  const float* be3 = (const float*)d_in[12];
  const float* wf1 = (const float*)d_in[13];
  const float* g4  = (const float*)d_in[15];
  const float* be4 = (const float*)d_in[16];
  const float* wf2 = (const float*)d_in[17];
  const float* bf2 = (const float*)d_in[18];
  float* out = (float*)d_out;

  char* W = (char*)d_ws;
  double* sum   = (double*)W;                 // 2048 dbl
  double* sumsq = sum + 2048;                 // ends 32768
  float*  scale = (float*)(W + 32768);
  float*  shift = scale + 2048;               // ends 49152
  float*    p1   = (float*)   (W + 65536);        // [B][196][64] f32 (dead after norm1)
  float*    c2   = (float*)   (W + 65536);        // [B][196][128] f32 (p1 dead)
  float*    p3   = (float*)   (W + 65536);        // [B][256][49] f32 (c2 dead)
  float*    f1   = (float*)   (W + 65536);        // [1024][2048] f32 (p3 dead)
  ushort_t* a3   = (ushort_t*)(W + 51445760);     // [B][256][49] bf16
  ushort_t* wf1b = (ushort_t*)(W + 77135872);     // [2048][12544] bf16
  ushort_t* a1   = (ushort_t*)(W + 102825984);    // [B][196][64] bf16 (dead after conv2)
  ushort_t* w2b  = (ushort_t*)(W + 128516096);    // [128][576]
  ushort_t* a2   = (ushort_t*)(W + 128663552);    // [B][196][128] bf16
  ushort_t* w3b  = (ushort_t*)(W + 180043776);    // [256][1152]
  float*    pS2  = (float*)   (W + 180633600);    // [1024][128]
  float*    pQ2  = pS2 + 131072;
  float*    pS3  = pQ2 + 131072;                  // [1024][256]
  float*    pQ3  = pS3 + 262144;
  float*    pSF  = pQ3 + 262144;                  // [16][2048]
  float*    pQF  = pSF + 32768;                   // ends ~184 MB

  // ---- layer 1 ----
  k_conv1_pool<<<50176, 256, 0, stream>>>(x, w1, p1);
  hipMemsetAsync(sum, 0, 32768, stream);
  k_stats_cl64<<<dim3(1,128), 256, 0, stream>>>(p1, sum, sumsq, 200704L);
  k_bnparams<<<1, 256, 0, stream>>>(sum, sumsq, g1, be1, scale, shift, 64, 48, 1.0/200704.0);
  k_norm_sign<<<50176, 256, 0, stream>>>(p1, a1, scale, shift, 64, 1, 12845056);
  // ---- layer 2 ----
  k_prep_w2<<<288, 256, 0, stream>>>(w2, w2b);
  k_prep_w3<<<1152, 256, 0, stream>>>(w3, w3b);
  k_conv2_mfma<<<dim3(2, B_), 256, 0, stream>>>(a1, w2b, c2, pS2, pQ2);
  hipMemsetAsync(sum, 0, 32768, stream);
  k_reduce_stats<<<dim3(1,32), 256, 0, stream>>>(pS2, pQ2, sum, sumsq, 128, 1024);
  k_bnparams<<<1, 256, 0, stream>>>(sum, sumsq, g2, be2, scale, shift, 128, 128, 1.0/200704.0);
  k_norm_sign<<<100352, 256, 0, stream>>>(c2, a2, scale, shift, 128, 1, 25690112);
  k_prep_wf1<<<25088, 256, 0, stream>>>(wf1, wf1b);
  // ---- layer 3 ----
  k_conv3_mfma_pool<<<dim3(4, B_), 256, 0, stream>>>(a2, w3b, p3, pS3, pQ3);
  hipMemsetAsync(sum, 0, 32768, stream);
  k_reduce_stats<<<dim3(1,32), 256, 0, stream>>>(pS3, pQ3, sum, sumsq, 256, 1024);
  k_bnparams<<<1, 256, 0, stream>>>(sum, sumsq, g3, be3, scale, shift, 256, 256, 1.0/50176.0);
  k_norm_sign<<<50176, 256, 0, stream>>>(p3, a3, scale, shift, 256, 49, 12845056);
  // ---- fc1 ----
  k_fc1_mfma<<<256, 256, 0, stream>>>(a3, wf1b, f1, pSF, pQF);
  hipMemsetAsync(sum, 0, 32768, stream);
  k_reduce_stats<<<dim3(8,1), 256, 0, stream>>>(pSF, pQF, sum, sumsq, 2048, 16);
  k_bnparams<<<8, 256, 0, stream>>>(sum, sumsq, g4, be4, scale, shift, 2048, 2048, 1.0/1024.0);
  k_norm_htanh<<<8192, 256, 0, stream>>>(f1, scale, shift, 2048, 2097152);
  // ---- fc2 + log_softmax ----
  k_fc2_lsm<<<B_, 256, 0, stream>>>(f1, wf2, bf2, out);
}